// Round 1
// baseline (223.721 us; speedup 1.0000x reference)
//
#include <hip/hip_runtime.h>

#define BATCH 4096
#define NN 62
#define FF 5
#define KC 4          // K+1 Chebyshev terms
#define CO 64
#define NSEL 31
#define NF (NN*FF)    // 310
#define NCO (NN*CO)   // 3968
#define NTHREADS 320  // 5 waves

__global__ __launch_bounds__(NTHREADS) void gnn_fused(
    const float* __restrict__ x, const float* __restrict__ adj,
    const int* __restrict__ mask_idx,
    const float* __restrict__ gc_w, const float* __restrict__ gc_b,
    const float* __restrict__ gc1_w, const float* __restrict__ gc1_b,
    const float* __restrict__ gc2_w, const float* __restrict__ gc2_b,
    const float* __restrict__ fc1_w, const float* __restrict__ fc1_b,
    const float* __restrict__ fc2_w, const float* __restrict__ fc2_b,
    const float* __restrict__ cls_w, const float* __restrict__ cls_b,
    float* __restrict__ out)
{
    __shared__ float s_adj[NN*NN];          // 3844
    __shared__ float s_x[NF];               // 310
    __shared__ float s_m[NN];
    __shared__ float s_dis1[NN], s_dis2[NN];
    __shared__ float s_xs1[KC][NF], s_xs2[KC][NF];   // 2*1240
    __shared__ float s_t1[NF], s_t2[NF];
    __shared__ float s_w1[KC*FF*CO], s_w2[KC*FF*CO], s_wg[KC*FF*CO]; // 3*1280
    __shared__ float s_b1[CO], s_b2[CO], s_bg[CO];
    __shared__ float s_red[5][8];

    const int b = blockIdx.x;
    const int t = threadIdx.x;

    // ---- stage inputs ----
    for (int i = t; i < NN*NN; i += NTHREADS) s_adj[i] = adj[i];
    for (int i = t; i < NF; i += NTHREADS)    s_x[i]   = x[b*NF + i];
    for (int i = t; i < KC*FF*CO; i += NTHREADS) {
        s_w1[i] = gc1_w[i]; s_w2[i] = gc2_w[i]; s_wg[i] = gc_w[i];
    }
    if (t < CO) { s_b1[t] = gc1_b[t]; s_b2[t] = gc2_b[t]; s_bg[t] = gc_b[t]; }
    if (t < NN) s_m[t] = 0.0f;
    __syncthreads();
    if (t < NSEL) s_m[mask_idx[b*NSEL + t]] = 1.0f;  // same-value races benign
    __syncthreads();

    // ---- degrees / dis vectors ----
    if (t < NN) {
        float d1 = 0.f, d2 = 0.f;
        for (int j = 0; j < NN; ++j) { float a = s_adj[t*NN+j]; d1 += a; d2 += a*s_m[j]; }
        d2 *= s_m[t];
        s_dis1[t] = (d1 > 0.f) ? rsqrtf(d1) : 0.f;
        s_dis2[t] = (d2 > 0.f) ? rsqrtf(d2) : 0.f;
    }
    __syncthreads();

    // ---- Chebyshev stacks (path1: L1,x ; path2: L2,x*m) ----
    if (t < NF) {
        int n = t / FF;
        s_xs1[0][t] = s_x[t];
        s_xs2[0][t] = s_x[t]*s_m[n];
    }
    __syncthreads();
    for (int k = 1; k < KC; ++k) {
        if (t < NF) {
            int n = t / FF;
            s_t1[t] = s_dis1[n]*s_xs1[k-1][t];
            s_t2[t] = s_dis2[n]*s_xs2[k-1][t];
        }
        __syncthreads();
        if (t < NF) {
            int n = t / FF, f = t - n*FF;
            float a1 = 0.f, a2 = 0.f;
            for (int j = 0; j < NN; ++j) {
                float a = s_adj[n*NN+j];
                a1 += a*s_t1[j*FF+f];
                a2 += a*s_t2[j*FF+f];
            }
            float c = (k == 1) ? 1.0f : 2.0f;
            float v1 = -c*s_dis1[n]*a1;
            float v2 = -c*s_dis2[n]*a2;
            if (k >= 2) { v1 -= s_xs1[k-2][t]; v2 -= s_xs2[k-2][t]; }
            s_xs1[k][t] = v1;
            s_xs2[k][t] = v2;
        }
        __syncthreads();
    }

    // ---- einsum + ReLU fused into FC partial accumulation ----
    float acc1[3] = {0,0,0}, acc2[3] = {0,0,0}, accg[2] = {0,0};
    for (int idx = t; idx < NCO; idx += NTHREADS) {
        int n = idx / CO, o = idx - n*CO;   // n wave-uniform, o == lane
        float h1 = s_b1[o], h2 = s_b2[o], hg = s_bg[o];
        #pragma unroll
        for (int k = 0; k < KC; ++k) {
            #pragma unroll
            for (int f = 0; f < FF; ++f) {
                float xv1 = s_xs1[k][n*FF+f];
                float xv2 = s_xs2[k][n*FF+f];
                int wi = (k*FF+f)*CO + o;
                h1 += xv1 * s_w1[wi];
                h2 += xv2 * s_w2[wi];
                hg += xv1 * s_wg[wi];
            }
        }
        h1 = fmaxf(h1, 0.f); h2 = fmaxf(h2, 0.f); hg = fmaxf(hg, 0.f);
        const float* f1 = fc1_w + idx*3;
        const float* f2 = fc2_w + idx*3;
        const float* fg = cls_w + idx*2;
        acc1[0] += h1*f1[0]; acc1[1] += h1*f1[1]; acc1[2] += h1*f1[2];
        acc2[0] += h2*f2[0]; acc2[1] += h2*f2[1]; acc2[2] += h2*f2[2];
        accg[0] += hg*fg[0]; accg[1] += hg*fg[1];
    }

    // ---- reduce 8 partials across 320 threads ----
    #pragma unroll
    for (int off = 32; off > 0; off >>= 1) {
        #pragma unroll
        for (int c = 0; c < 3; ++c) {
            acc1[c] += __shfl_down(acc1[c], off);
            acc2[c] += __shfl_down(acc2[c], off);
        }
        accg[0] += __shfl_down(accg[0], off);
        accg[1] += __shfl_down(accg[1], off);
    }
    const int wave = t >> 6, lane = t & 63;
    if (lane == 0) {
        s_red[wave][0] = acc1[0]; s_red[wave][1] = acc1[1]; s_red[wave][2] = acc1[2];
        s_red[wave][3] = acc2[0]; s_red[wave][4] = acc2[1]; s_red[wave][5] = acc2[2];
        s_red[wave][6] = accg[0]; s_red[wave][7] = accg[1];
    }
    __syncthreads();
    if (t == 0) {
        float r[8];
        #pragma unroll
        for (int i = 0; i < 8; ++i) {
            float s = 0.f;
            for (int w = 0; w < 5; ++w) s += s_red[w][i];
            r[i] = s;
        }
        float l1c[3], l2c[3];
        #pragma unroll
        for (int c = 0; c < 3; ++c) { l1c[c] = r[c] + fc1_b[c]; l2c[c] = r[3+c] + fc2_b[c]; }
        float g0 = r[6] + cls_b[0], g1 = r[7] + cls_b[1];
        float mx = fmaxf(g0, g1);
        float e0 = expf(g0 - mx), e1 = expf(g1 - mx);
        float inv = 1.0f / (e0 + e1);
        float p0 = e0*inv, p1 = e1*inv;
        out[b*3+0] = l1c[0]*p0 + l2c[0]*p1;
        out[b*3+1] = l1c[1]*p0 + l2c[1]*p1;
        out[b*3+2] = l1c[2]*p0 + l2c[2]*p1;
    }
}

extern "C" void kernel_launch(void* const* d_in, const int* in_sizes, int n_in,
                              void* d_out, int out_size, void* d_ws, size_t ws_size,
                              hipStream_t stream) {
    const float* x      = (const float*)d_in[0];
    const float* adj    = (const float*)d_in[1];
    const int*   midx   = (const int*)  d_in[2];
    const float* gc_w   = (const float*)d_in[3];
    const float* gc_b   = (const float*)d_in[4];
    const float* gc1_w  = (const float*)d_in[5];
    const float* gc1_b  = (const float*)d_in[6];
    const float* gc2_w  = (const float*)d_in[7];
    const float* gc2_b  = (const float*)d_in[8];
    const float* fc1_w  = (const float*)d_in[9];
    const float* fc1_b  = (const float*)d_in[10];
    const float* fc2_w  = (const float*)d_in[11];
    const float* fc2_b  = (const float*)d_in[12];
    const float* cls_w  = (const float*)d_in[13];
    const float* cls_b  = (const float*)d_in[14];
    float* o = (float*)d_out;
    hipLaunchKernelGGL(gnn_fused, dim3(BATCH), dim3(NTHREADS), 0, stream,
        x, adj, midx, gc_w, gc_b, gc1_w, gc1_b, gc2_w, gc2_b,
        fc1_w, fc1_b, fc2_w, fc2_b, cls_w, cls_b, o);
}

// Round 2
// 91.976 us; speedup vs baseline: 2.4324x; 2.4324x over previous
//
#include <hip/hip_runtime.h>

#define BATCH 4096
#define NN 62
#define FF 5
#define KC 4          // K+1 Chebyshev terms
#define CO 64
#define NSEL 31
#define NF (NN*FF)    // 310
#define KF (KC*FF)    // 20
#define ADJ_S 68      // padded adj/u row stride (float4-aligned, bank-rotating)
#define XS_S 24       // padded xs row stride (20 used, 16B-aligned rows)
#define NTHREADS 320  // 5 waves

__global__ __launch_bounds__(NTHREADS, 6) void gnn_fused(
    const float* __restrict__ x, const float* __restrict__ adj,
    const int* __restrict__ mask_idx,
    const float* __restrict__ gc_w, const float* __restrict__ gc_b,
    const float* __restrict__ gc1_w, const float* __restrict__ gc1_b,
    const float* __restrict__ gc2_w, const float* __restrict__ gc2_b,
    const float* __restrict__ fc1_w, const float* __restrict__ fc1_b,
    const float* __restrict__ fc2_w, const float* __restrict__ fc2_b,
    const float* __restrict__ cls_w, const float* __restrict__ cls_b,
    float* __restrict__ out)
{
    __shared__ __align__(16) float s_adj[NN*ADJ_S];   // 16864 B, cols 62..67 zeroed
    __shared__ __align__(16) float s_xs1[NN*XS_S];    // 5952 B  [n][k*5+f]
    __shared__ __align__(16) float s_xs2[NN*XS_S];    // 5952 B
    __shared__ __align__(16) float s_u1[FF*ADJ_S];    // 1360 B  [f][j] dis1-scaled
    __shared__ __align__(16) float s_u2[FF*ADJ_S];    // 1360 B
    __shared__ __align__(16) float s_m[64];           // mask, padded w/ zeros
    __shared__ float s_dis1[NN], s_dis2[NN];
    __shared__ float s_red[5][8];

    const int b = blockIdx.x;
    const int t = threadIdx.x;

    // ---- stage: adj (zero-padded), u-pad zeros, mask zeros, x -> xs[k=0] ----
    for (int i = t; i < NN*ADJ_S; i += NTHREADS) {
        int r = i / ADJ_S, c = i - r*ADJ_S;
        s_adj[i] = (c < NN) ? adj[r*NN + c] : 0.0f;
    }
    for (int i = t; i < FF*ADJ_S; i += NTHREADS) { s_u1[i] = 0.0f; s_u2[i] = 0.0f; }
    if (t < 64) s_m[t] = 0.0f;
    for (int i = t; i < NF; i += NTHREADS) {
        int n = i / FF, f = i - n*FF;
        s_xs1[n*XS_S + f] = x[b*NF + i];
    }
    __syncthreads();
    if (t < NSEL) s_m[mask_idx[b*NSEL + t]] = 1.0f;   // same-value races benign
    __syncthreads();

    // ---- xs2[0] = x*m  and  degrees (vectorized float4 rows) ----
    if (t < NF) {
        int n = t / FF, f = t - n*FF;
        s_xs2[n*XS_S + f] = s_xs1[n*XS_S + f] * s_m[n];
    }
    if (t < NN) {
        const float4* ar = (const float4*)&s_adj[t*ADJ_S];
        const float4* mr = (const float4*)&s_m[0];
        float4 d1v = make_float4(0,0,0,0), d2v = make_float4(0,0,0,0);
        #pragma unroll
        for (int j4 = 0; j4 < 16; ++j4) {
            float4 a = ar[j4], m4 = mr[j4];
            d1v.x += a.x; d1v.y += a.y; d1v.z += a.z; d1v.w += a.w;
            d2v.x += a.x*m4.x; d2v.y += a.y*m4.y; d2v.z += a.z*m4.z; d2v.w += a.w*m4.w;
        }
        float d1 = d1v.x + d1v.y + d1v.z + d1v.w;
        float d2 = (d2v.x + d2v.y + d2v.z + d2v.w) * s_m[t];
        s_dis1[t] = (d1 > 0.f) ? rsqrtf(d1) : 0.f;
        s_dis2[t] = (d2 > 0.f) ? rsqrtf(d2) : 0.f;
    }
    __syncthreads();

    // ---- Chebyshev recursion, both paths ----
    const int n_id = t / FF, f_id = t - n_id*FF;   // valid when t < NF
    for (int k = 1; k < KC; ++k) {
        if (t < NF) {
            float xp1 = s_xs1[n_id*XS_S + (k-1)*FF + f_id];
            float xp2 = s_xs2[n_id*XS_S + (k-1)*FF + f_id];
            s_u1[f_id*ADJ_S + n_id] = s_dis1[n_id] * xp1;
            s_u2[f_id*ADJ_S + n_id] = s_dis2[n_id] * xp2;
        }
        __syncthreads();
        if (t < NF) {
            const float4* ar  = (const float4*)&s_adj[n_id*ADJ_S];
            const float4* u1r = (const float4*)&s_u1[f_id*ADJ_S];
            const float4* u2r = (const float4*)&s_u2[f_id*ADJ_S];
            float4 a1 = make_float4(0,0,0,0), a2 = make_float4(0,0,0,0);
            #pragma unroll
            for (int j4 = 0; j4 < 16; ++j4) {
                float4 av = ar[j4], v1 = u1r[j4], v2 = u2r[j4];
                a1.x += av.x*v1.x; a1.y += av.y*v1.y; a1.z += av.z*v1.z; a1.w += av.w*v1.w;
                a2.x += av.x*v2.x; a2.y += av.y*v2.y; a2.z += av.z*v2.z; a2.w += av.w*v2.w;
            }
            float s1 = a1.x + a1.y + a1.z + a1.w;
            float s2 = a2.x + a2.y + a2.z + a2.w;
            float c = (k == 1) ? 1.0f : 2.0f;
            float v1 = -c * s_dis1[n_id] * s1;
            float v2 = -c * s_dis2[n_id] * s2;
            if (k >= 2) {
                v1 -= s_xs1[n_id*XS_S + (k-2)*FF + f_id];
                v2 -= s_xs2[n_id*XS_S + (k-2)*FF + f_id];
            }
            s_xs1[n_id*XS_S + k*FF + f_id] = v1;
            s_xs2[n_id*XS_S + k*FF + f_id] = v2;
        }
        __syncthreads();
    }

    // ---- einsum + ReLU + FC, one head per pass (weights in VGPRs) ----
    const int w = t >> 6, o = t & 63;

    auto head_pass = [&](const float* __restrict__ wsrc, const float* __restrict__ bsrc,
                         const float* __restrict__ fsrc, const float* __restrict__ xs,
                         int nouts, int slot) {
        float4 wr[5];
        #pragma unroll
        for (int c = 0; c < 5; ++c)
            wr[c] = make_float4(wsrc[(4*c+0)*CO + o], wsrc[(4*c+1)*CO + o],
                                wsrc[(4*c+2)*CO + o], wsrc[(4*c+3)*CO + o]);
        float bias = bsrc[o];
        float a0 = 0.f, a1 = 0.f, a2 = 0.f;
        for (int n = w; n < NN; n += 5) {
            const float4* xr = (const float4*)&xs[n*XS_S];
            float4 hv = make_float4(0,0,0,0);
            #pragma unroll
            for (int c = 0; c < 5; ++c) {
                float4 xv = xr[c];
                hv.x += xv.x*wr[c].x; hv.y += xv.y*wr[c].y;
                hv.z += xv.z*wr[c].z; hv.w += xv.w*wr[c].w;
            }
            float h = fmaxf(bias + hv.x + hv.y + hv.z + hv.w, 0.f);
            const float* fp = fsrc + (n*CO + o)*nouts;
            a0 += h*fp[0]; a1 += h*fp[1];
            if (nouts == 3) a2 += h*fp[2];
        }
        #pragma unroll
        for (int off = 32; off > 0; off >>= 1) {
            a0 += __shfl_down(a0, off);
            a1 += __shfl_down(a1, off);
            if (nouts == 3) a2 += __shfl_down(a2, off);
        }
        if (o == 0) {
            s_red[w][slot+0] = a0; s_red[w][slot+1] = a1;
            if (nouts == 3) s_red[w][slot+2] = a2;
        }
    };

    head_pass(gc1_w, gc1_b, fc1_w, s_xs1, 3, 0);
    head_pass(gc2_w, gc2_b, fc2_w, s_xs2, 3, 3);
    head_pass(gc_w,  gc_b,  cls_w, s_xs1, 2, 6);
    __syncthreads();

    // ---- epilogue: combine partials, softmax gate ----
    if (t == 0) {
        float r[8];
        #pragma unroll
        for (int i = 0; i < 8; ++i) {
            float s = 0.f;
            for (int wv = 0; wv < 5; ++wv) s += s_red[wv][i];
            r[i] = s;
        }
        float l1c[3], l2c[3];
        #pragma unroll
        for (int c = 0; c < 3; ++c) { l1c[c] = r[c] + fc1_b[c]; l2c[c] = r[3+c] + fc2_b[c]; }
        float g0 = r[6] + cls_b[0], g1 = r[7] + cls_b[1];
        float mx = fmaxf(g0, g1);
        float e0 = expf(g0 - mx), e1 = expf(g1 - mx);
        float inv = 1.0f / (e0 + e1);
        float p0 = e0*inv, p1 = e1*inv;
        out[b*3+0] = l1c[0]*p0 + l2c[0]*p1;
        out[b*3+1] = l1c[1]*p0 + l2c[1]*p1;
        out[b*3+2] = l1c[2]*p0 + l2c[2]*p1;
    }
}

extern "C" void kernel_launch(void* const* d_in, const int* in_sizes, int n_in,
                              void* d_out, int out_size, void* d_ws, size_t ws_size,
                              hipStream_t stream) {
    const float* x      = (const float*)d_in[0];
    const float* adj    = (const float*)d_in[1];
    const int*   midx   = (const int*)  d_in[2];
    const float* gc_w   = (const float*)d_in[3];
    const float* gc_b   = (const float*)d_in[4];
    const float* gc1_w  = (const float*)d_in[5];
    const float* gc1_b  = (const float*)d_in[6];
    const float* gc2_w  = (const float*)d_in[7];
    const float* gc2_b  = (const float*)d_in[8];
    const float* fc1_w  = (const float*)d_in[9];
    const float* fc1_b  = (const float*)d_in[10];
    const float* fc2_w  = (const float*)d_in[11];
    const float* fc2_b  = (const float*)d_in[12];
    const float* cls_w  = (const float*)d_in[13];
    const float* cls_b  = (const float*)d_in[14];
    float* o = (float*)d_out;
    hipLaunchKernelGGL(gnn_fused, dim3(BATCH), dim3(NTHREADS), 0, stream,
        x, adj, midx, gc_w, gc_b, gc1_w, gc1_b, gc2_w, gc2_b,
        fc1_w, fc1_b, fc2_w, fc2_b, cls_w, cls_b, o);
}